// Round 5
// baseline (1524.387 us; speedup 1.0000x reference)
//
#include <hip/hip_runtime.h>
#include <stdint.h>

typedef unsigned short u16;
typedef unsigned int   u32;
typedef __attribute__((ext_vector_type(8)))  short s8v;
typedef __attribute__((ext_vector_type(16))) float f16v;
typedef __attribute__((ext_vector_type(2)))  float f2v;

#define JJ 17
#define CC 128
#define BB 3
#define ROWS (BB*JJ)     // 51
#define PP 64
#define XPD 132          // xhl pitch (dwords): 528B rows, 16B-aligned, bank stride 4
#define H1P 130          // h1 pitch (dwords)
#define NLAYERS 5
#define NT 256

#define XHL_OFF  0
#define H1_OFF   (PP*XPD*4)              // 33792
#define ADJ_OFF  (H1_OFF + PP*H1P*4)     // 33792+33280 = 67072
#define DIAG_OFF (ADJ_OFF + 1168)        // 68240
#define BIAS_OFF (DIAG_OFF + 256)        // 68496
#define LDS_BYTES (BIAS_OFF + 512)       // 69008 -> 2 blocks/CU

#define MFMA __builtin_amdgcn_mfma_f32_32x32x16_bf16

__device__ __forceinline__ u16 f2bf(float f) {
  u32 u = __float_as_uint(f);
  u += 0x7FFFu + ((u >> 16) & 1u);   // RNE
  return (u16)(u >> 16);
}
__device__ __forceinline__ float bf2f(u16 h) {
  return __uint_as_float(((u32)h) << 16);
}
__device__ __forceinline__ float wred(float v) {
  #pragma unroll
  for (int m = 32; m >= 1; m >>= 1) v += __shfl_xor(v, m, 64);
  return v;
}
__device__ __forceinline__ s8v u4s8(uint4 v) {
  union { uint4 u; s8v s; } c; c.u = v; return c.s;
}

// ---- setup: split W0/W1 into hi/lo bf16, frag layout ws[w][col][k] ----
__global__ void __launch_bounds__(256)
wprep(const float* __restrict__ W0, const float* __restrict__ W1,
      u16* __restrict__ wsH, u16* __restrict__ wsL)
{
  __shared__ float wt[64*130];
  const int w01 = blockIdx.x;
  const float* Wp = w01 ? W1 : W0;
  const int tid = threadIdx.x;
  for (int kh = 0; kh < 2; ++kh) {
    if (kh) __syncthreads();
    #pragma unroll
    for (int i = 0; i < 32; ++i) {
      int idx = tid + i*256;           // [64 kk][128 col], coalesced read
      int kk = idx >> 7, col = idx & 127;
      wt[kk*130 + col] = Wp[(kh*64 + kk)*128 + col];
    }
    __syncthreads();
    #pragma unroll
    for (int i = 0; i < 32; ++i) {
      int idx = tid + i*256;           // [128 col][64 kk], coalesced write
      int col = idx >> 6, kk = idx & 63;
      float v = wt[kk*130 + col];
      u16 h = f2bf(v);
      size_t o = (size_t)(w01*128 + col)*128 + kh*64 + kk;
      wsH[o] = h;
      wsL[o] = f2bf(v - bf2f(h));
    }
  }
}

__global__ void __launch_bounds__(NT, 2)
gconv_fused(const float* __restrict__ x, const float* __restrict__ x0,
            const float* __restrict__ adj, const u16* __restrict__ wsH,
            const u16* __restrict__ wsL, const float* __restrict__ bvec,
            const float* __restrict__ gamma, const float* __restrict__ beta,
            float* __restrict__ out, int totRows)
{
  extern __shared__ char smem[];
  u32*   xhl   = (u32*)(smem + XHL_OFF);     // [PP][XPD]: hi | lo<<16
  float* h1    = (float*)(smem + H1_OFF);    // [PP][H1P]
  float* adjs  = (float*)(smem + ADJ_OFF);   // [289] 0.8*adj, diag zeroed
  float* diag8 = (float*)(smem + DIAG_OFF);  // [64]
  float* biasl = (float*)(smem + BIAS_OFF);  // [128]

  const int tid  = threadIdx.x;
  const int lane = tid & 63;
  const int wid  = tid >> 6;        // 0..3 = N-tile
  const int g    = lane >> 5;
  const int nl   = lane & 31;
  const int ccol = wid*32 + nl;
  const int grow0 = blockIdx.x * ROWS;

  // ---- W fragments straight into registers from precomputed ws (L2-hot)
  s8v whi[2][8], wlo[2][8];
  #pragma unroll
  for (int w01 = 0; w01 < 2; ++w01) {
    const u16* bh = wsH + (size_t)(w01*128 + ccol)*128;
    const u16* bl = wsL + (size_t)(w01*128 + ccol)*128;
    #pragma unroll
    for (int ks = 0; ks < 8; ++ks) {
      whi[w01][ks] = u4s8(*(const uint4*)&bh[ks*16 + 8*g]);
      wlo[w01][ks] = u4s8(*(const uint4*)&bl[ks*16 + 8*g]);
    }
  }

  // ---- x -> packed xhl (float4 in, b128 out); pad rows zero
  #pragma unroll
  for (int i = 0; i < 8; ++i) {
    int el4 = tid + i*NT;             // 2048 float4 = 64 rows x 128
    int r = el4 >> 5, c4 = (el4 & 31) << 2;
    float4 v = make_float4(0.f, 0.f, 0.f, 0.f);
    if (r < ROWS && (grow0 + r) < totRows)
      v = *(const float4*)&x[(size_t)(grow0 + r)*CC + c4];
    uint4 p;
    {
      u16 h0 = f2bf(v.x), h1v = f2bf(v.y), h2 = f2bf(v.z), h3 = f2bf(v.w);
      p.x = (u32)h0 | ((u32)f2bf(v.x - bf2f(h0)) << 16);
      p.y = (u32)h1v | ((u32)f2bf(v.y - bf2f(h1v)) << 16);
      p.z = (u32)h2 | ((u32)f2bf(v.z - bf2f(h2)) << 16);
      p.w = (u32)h3 | ((u32)f2bf(v.w - bf2f(h3)) << 16);
    }
    *(uint4*)&xhl[r*XPD + c4] = p;
  }
  for (int t = tid; t < JJ*JJ; t += NT) {
    int j = t / JJ, k = t - j*JJ;
    adjs[t] = (j == k) ? 0.f : 0.8f * adj[t];
  }
  if (tid < PP) {
    int j = tid % JJ;
    diag8[tid] = (tid < ROWS) ? 0.8f * adj[j*JJ + j] : 0.f;
  }
  if (tid >= 128 && tid < 256) biasl[tid - 128] = bvec[tid - 128];
  __syncthreads();

  // ================= layer loop =================
  #pragma unroll 1
  for (int layer = 0; layer < NLAYERS; ++layer) {
    f16v acc0[2], acc1[2];
    #pragma unroll
    for (int mt = 0; mt < 2; ++mt)
      #pragma unroll
      for (int i = 0; i < 16; ++i) { acc0[mt][i] = 0.f; acc1[mt][i] = 0.f; }

    // ---- GEMM: 2x ds_read_b128 + 8 v_perm + 6 MFMA per (ks,mt)
    #pragma unroll
    for (int ks = 0; ks < 8; ++ks) {
      #pragma unroll
      for (int mt = 0; mt < 2; ++mt) {
        const u32* p = &xhl[(mt*32 + nl)*XPD + ks*16 + 8*g];
        uint4 P0 = *(const uint4*)p;
        uint4 P1 = *(const uint4*)(p + 4);
        union { u32 d[4]; s8v s; } ah, al;
        ah.d[0] = __builtin_amdgcn_perm(P0.y, P0.x, 0x05040100u);
        al.d[0] = __builtin_amdgcn_perm(P0.y, P0.x, 0x07060302u);
        ah.d[1] = __builtin_amdgcn_perm(P0.w, P0.z, 0x05040100u);
        al.d[1] = __builtin_amdgcn_perm(P0.w, P0.z, 0x07060302u);
        ah.d[2] = __builtin_amdgcn_perm(P1.y, P1.x, 0x05040100u);
        al.d[2] = __builtin_amdgcn_perm(P1.y, P1.x, 0x07060302u);
        ah.d[3] = __builtin_amdgcn_perm(P1.w, P1.z, 0x05040100u);
        al.d[3] = __builtin_amdgcn_perm(P1.w, P1.z, 0x07060302u);
        acc0[mt] = MFMA(ah.s, whi[0][ks], acc0[mt], 0, 0, 0);
        acc0[mt] = MFMA(al.s, whi[0][ks], acc0[mt], 0, 0, 0);
        acc0[mt] = MFMA(ah.s, wlo[0][ks], acc0[mt], 0, 0, 0);
        acc1[mt] = MFMA(ah.s, whi[1][ks], acc1[mt], 0, 0, 0);
        acc1[mt] = MFMA(al.s, whi[1][ks], acc1[mt], 0, 0, 0);
        acc1[mt] = MFMA(ah.s, wlo[1][ks], acc1[mt], 0, 0, 0);
      }
      __builtin_amdgcn_sched_barrier(0);   // cap fragment liveness per K-step
    }

    // ---- epilogue: acc1 (X@W1) -> h1 (separate buffer, no alias)
    #pragma unroll
    for (int mt = 0; mt < 2; ++mt)
      #pragma unroll
      for (int q = 0; q < 16; ++q) {
        int row = mt*32 + (q&3) + 8*(q>>2) + 4*g;
        h1[row*H1P + ccol] = acc1[mt][q];
      }
    __syncthreads();

    // ---- joint mix in place (wave wid = batch elem; wave 3 idles)
    if (wid < BB) {
      const int rb = wid * JJ;
      f2v h[JJ];
      #pragma unroll
      for (int k = 0; k < JJ; ++k)
        h[k] = *(const f2v*)&h1[(rb+k)*H1P + 2*lane];
      #pragma unroll 1
      for (int j = 0; j < JJ; ++j) {
        f2v m; m.x = 0.f; m.y = 0.f;
        #pragma unroll
        for (int k = 0; k < JJ; ++k) {
          float a = adjs[j*JJ + k];
          m.x += a * h[k].x; m.y += a * h[k].y;
        }
        *(f2v*)&h1[(rb+j)*H1P + 2*lane] = m;
      }
    }
    __syncthreads();

    // ---- combine (single pass): x = 0.2*x0 + diag*H0 + M1 + b -> packed xhl
    #pragma unroll
    for (int mt = 0; mt < 2; ++mt)
      #pragma unroll
      for (int q = 0; q < 16; ++q) {
        int row = mt*32 + (q&3) + 8*(q>>2) + 4*g;
        int grow = grow0 + row;
        float x0v = (row < ROWS && grow < totRows) ? x0[(size_t)grow*CC + ccol] : 0.f;
        float v = 0.2f*x0v + diag8[row]*acc0[mt][q] + h1[row*H1P + ccol] + biasl[ccol];
        u16 hh = f2bf(v);
        xhl[row*XPD + ccol] = (u32)hh | ((u32)f2bf(v - bf2f(hh)) << 16);
      }
    __syncthreads();
  }

  // ---- LayerNorm + store
  float ga = gamma[lane], g2 = gamma[64+lane];
  float ba = beta[lane],  b2 = beta[64+lane];
  #pragma unroll 1
  for (int i = 0; i < 16; ++i) {
    int r = wid + 4*i;               // wave-uniform
    if (r >= ROWS) continue;
    int grow = grow0 + r;
    if (grow >= totRows) continue;
    u32 pa = xhl[r*XPD + lane];
    u32 pc = xhl[r*XPD + 64 + lane];
    float xa = bf2f((u16)pa) + bf2f((u16)(pa >> 16));
    float xc = bf2f((u16)pc) + bf2f((u16)(pc >> 16));
    float mu = wred(xa + xc) * (1.f/128.f);
    float da = xa - mu, dc = xc - mu;
    float vs = wred(da*da + dc*dc) * (1.f/128.f);
    float rs = rsqrtf(vs + 1e-10f);
    size_t ob = (size_t)grow*CC;
    out[ob + lane]      = da*rs*ga + ba;
    out[ob + 64 + lane] = dc*rs*g2 + b2;
  }
}

extern "C" void kernel_launch(void* const* d_in, const int* in_sizes, int n_in,
                              void* d_out, int out_size, void* d_ws, size_t ws_size,
                              hipStream_t stream) {
  const float* x   = (const float*)d_in[0];
  const float* x0  = (const float*)d_in[1];
  const float* adj = (const float*)d_in[2];
  const float* W0  = (const float*)d_in[3];
  const float* W1  = (const float*)d_in[4];
  const float* bv  = (const float*)d_in[5];
  const float* ga  = (const float*)d_in[6];
  const float* be  = (const float*)d_in[7];
  u16* wsH = (u16*)d_ws;                    // [2][128][128] bf16 hi
  u16* wsL = wsH + 2*128*128;               // [2][128][128] bf16 lo
  int totRows = in_sizes[0] / CC;
  int nBatch  = totRows / JJ;
  int grid    = (nBatch + BB - 1) / BB;
  wprep<<<dim3(2), dim3(256), 0, stream>>>(W0, W1, wsH, wsL);
  hipFuncSetAttribute((const void*)gconv_fused,
                      hipFuncAttributeMaxDynamicSharedMemorySize, LDS_BYTES);
  gconv_fused<<<dim3(grid), dim3(NT), LDS_BYTES, stream>>>(
      x, x0, adj, wsH, wsL, bv, ga, be, (float*)d_out, totRows);
}